// Round 1
// baseline (98.804 us; speedup 1.0000x reference)
//
#include <hip/hip_runtime.h>

#define N_INPUTS 16384
#define N_DET    65536
#define KD       32
#define BATCH    32
#define SLICES   16                        // det slices; slice -> fixed XCD
#define PAIRS    (BATCH / 2)               // 16 batch pairs
#define DPB      (N_DET / SLICES)          // 4096 detectors per block
#define THREADS  1024                      // 16 waves, 1 block/CU (160 KB LDS)

#define DEG_BLOCKS     64
#define DET_PER_DEGBLK (N_DET / DEG_BLOCKS)   // 1024
#define DEG_WORDS      (N_INPUTS / 4)         // 4096 u32, byte-packed u8 counts
#define WC_WORDS       (N_INPUTS / 2)         // 8192 u32: 2 inputs x 2 batches (u8)

__device__ __forceinline__ float max3f(float a, float b, float c) {
    return fmaxf(fmaxf(a, b), c);          // fuses to v_max3_f32
}

// ---------------------------------------------------------------------------
// Win-count formulation: input i spikes for batch b iff it was the (first-max)
// winner of EVERY detector membership it has:
//     loser_count[b][i] == 0  <=>  win_count[b][i] == degree[i]
// degree[] is batch-independent -> counted ONCE per launch instead of folding
// 32 per-slot scatter atomics into every (detector, batch-pair) instance.
// ---------------------------------------------------------------------------

// degree partials: block counts membership multiplicity of 1024 detectors into
// byte-packed LDS (max per-block byte ~10, max total degree ~180 < 255: safe).
__global__ __launch_bounds__(1024) void degree_count(const int* __restrict__ det,
                                                     unsigned* __restrict__ degp) {
    __shared__ unsigned dl[DEG_WORDS];      // 16 KB, input i -> byte i&3 of word i>>2
    const int tid = threadIdx.x;
#pragma unroll
    for (int k = 0; k < DEG_WORDS / 1024; ++k) dl[tid + k * 1024] = 0u;
    __syncthreads();

    const int d = blockIdx.x * DET_PER_DEGBLK + tid;   // one detector per thread
    const int4* drow = (const int4*)det + (size_t)d * (KD / 4);
#pragma unroll
    for (int q = 0; q < KD / 4; ++q) {
        int4 r = drow[q];
        atomicAdd(&dl[r.x >> 2], 1u << (8 * (r.x & 3)));
        atomicAdd(&dl[r.y >> 2], 1u << (8 * (r.y & 3)));
        atomicAdd(&dl[r.z >> 2], 1u << (8 * (r.z & 3)));
        atomicAdd(&dl[r.w >> 2], 1u << (8 * (r.w & 3)));
    }
    __syncthreads();

    unsigned* out = degp + (size_t)blockIdx.x * DEG_WORDS;
#pragma unroll
    for (int k = 0; k < DEG_WORDS / 1024; ++k)
        out[tid + k * 1024] = dl[tid + k * 1024];
}

// ---------------------------------------------------------------------------
// One block = (2 batch rows interleaved in LDS as float2) x (one detector
// slice). Per detector: 32-deep ds_read_b64 gather burst serves both batches;
// max via v_max3 tree; winner ID via backward cndmask chain over ids[s]
// (compile-time indices only -> no scratch; exact first-max tie-break, which
// also handles duplicate ids / exact float ties). Then just TWO fire-and-
// forget LDS atomicAdds per detector (one winner per batch) into byte-packed
// win counters -- the 32-atomicOr per-slot scatter is gone.
// ---------------------------------------------------------------------------
__global__ __launch_bounds__(THREADS) void inhibit(const float* __restrict__ x,
                                                   const int* __restrict__ det,
                                                   unsigned* __restrict__ wp) {
    __shared__ float2   xs[N_INPUTS];       // 128 KB: [id] -> (x_b0, x_b1)
    __shared__ unsigned wc[WC_WORDS];       // 32 KB: input i, batch q -> byte (i&1)*2+q

    const int slice = blockIdx.x;
    const int pair  = blockIdx.y;
    const int tid   = threadIdx.x;

#pragma unroll
    for (int k = 0; k < WC_WORDS / THREADS; ++k) wc[tid + k * THREADS] = 0u;

    // stage both rows interleaved: xs[i] = (x[b0][i], x[b1][i])
    const float4* x0 = (const float4*)(x + (size_t)(2 * pair) * N_INPUTS);
    const float4* x1 = (const float4*)(x + (size_t)(2 * pair + 1) * N_INPUTS);
    float4* xs4 = (float4*)xs;
#pragma unroll
    for (int k = 0; k < N_INPUTS / 4 / THREADS; ++k) {
        int t = tid + k * THREADS;
        float4 a = x0[t], b = x1[t];
        xs4[2 * t + 0] = make_float4(a.x, b.x, a.y, b.y);
        xs4[2 * t + 1] = make_float4(a.z, b.z, a.w, b.w);
    }
    __syncthreads();

    const int4* det4 = (const int4*)det;
#pragma unroll 1
    for (int j = 0; j < DPB / THREADS; ++j) {      // 4 detectors per thread
        const int   d    = slice * DPB + j * THREADS + tid;
        const int4* drow = det4 + (size_t)d * 8;
        int ids[KD];
#pragma unroll
        for (int q = 0; q < 8; ++q) {
            int4 r = drow[q];
            ids[q * 4 + 0] = r.x; ids[q * 4 + 1] = r.y;
            ids[q * 4 + 2] = r.z; ids[q * 4 + 3] = r.w;
        }

        float2 v[KD];                              // 32-deep ds_read_b64 burst
#pragma unroll
        for (int s = 0; s < KD; ++s) v[s] = xs[ids[s]];

        // max3 tree per batch (exact: fmax/max3 return an input bit-for-bit)
        float t0[11], t1[11];
#pragma unroll
        for (int i = 0; i < 10; ++i) {
            t0[i] = max3f(v[3 * i].x, v[3 * i + 1].x, v[3 * i + 2].x);
            t1[i] = max3f(v[3 * i].y, v[3 * i + 1].y, v[3 * i + 2].y);
        }
        t0[10] = fmaxf(v[30].x, v[31].x);
        t1[10] = fmaxf(v[30].y, v[31].y);
        float m0 = fmaxf(max3f(max3f(t0[0], t0[1], t0[2]),
                               max3f(t0[3], t0[4], t0[5]),
                               max3f(t0[6], t0[7], t0[8])),
                         fmaxf(t0[9], t0[10]));
        float m1 = fmaxf(max3f(max3f(t1[0], t1[1], t1[2]),
                               max3f(t1[3], t1[4], t1[5]),
                               max3f(t1[6], t1[7], t1[8])),
                         fmaxf(t1[9], t1[10]));

        // first-max winner ID per batch: backward overwrite chain (2 ops/slot),
        // compile-time ids[] indices only (no scratch spill)
        int i0 = ids[0], i1 = ids[0];
#pragma unroll
        for (int s = KD - 1; s >= 0; --s) {
            i0 = (v[s].x == m0) ? ids[s] : i0;
            i1 = (v[s].y == m1) ? ids[s] : i1;
        }

        // one win per detector per batch (byte-packed; per-slice wins <= ~25)
        atomicAdd(&wc[i0 >> 1], 1u << (8 * ((i0 & 1) * 2 + 0)));
        atomicAdd(&wc[i1 >> 1], 1u << (8 * ((i1 & 1) * 2 + 1)));
    }
    __syncthreads();

    unsigned* out = wp + (size_t)(slice * PAIRS + pair) * WC_WORDS;
#pragma unroll
    for (int k = 0; k < WC_WORDS / THREADS; ++k)
        out[tid + k * THREADS] = wc[tid + k * THREADS];
}

// ---------------------------------------------------------------------------
// finalize: block k covers inputs [64k, 64k+64) x all 32 batches.
// Phase 1: reduce the 64 degree partials for these inputs in-block (packed-
// byte u32 adds; byte sums <= ~180, carry-safe). Phase 2: per output, sum the
// 16 slice win-partials (packed-byte, <= degree <= ~180) and compare.
// ---------------------------------------------------------------------------
__global__ __launch_bounds__(1024) void finalize(const unsigned* __restrict__ wp,
                                                 const unsigned* __restrict__ degp,
                                                 float* __restrict__ out) {
    __shared__ unsigned red[1024];
    const int k = blockIdx.x, t = threadIdx.x;

    // t = partial(t>>4) x word(t&15); reduce over the 64 partials
    red[t] = degp[(size_t)(t >> 4) * DEG_WORDS + k * 16 + (t & 15)];
    __syncthreads();
#pragma unroll
    for (int off = 512; off >= 16; off >>= 1) {
        if (t < off) red[t] += red[t + off];
        __syncthreads();
    }
    // red[w], w<16: packed degree bytes for inputs 64k+4w .. 64k+4w+3

    const int b  = t & 31;          // batch
    const int jp = t >> 5;          // input pair 0..31 -> i0 = 64k+2*jp
    const int p  = b >> 1, q = b & 1;

    unsigned wsum = 0;
#pragma unroll
    for (int s = 0; s < SLICES; ++s)
        wsum += wp[(size_t)(s * PAIRS + p) * WC_WORDS + k * 32 + jp];

    const unsigned w0 = (wsum >> (8 * q)) & 255u;        // even input, batch b
    const unsigned w1 = (wsum >> (8 * (2 + q))) & 255u;  // odd  input, batch b

    const unsigned dw = red[jp >> 1];
    const int      sh = (2 * jp) & 3;                    // 0 or 2
    const unsigned d0 = (dw >> (8 * sh)) & 255u;
    const unsigned d1 = (dw >> (8 * (sh + 1))) & 255u;

    float2 r;
    r.x = (w0 == d0) ? 1.0f : 0.0f;
    r.y = (w1 == d1) ? 1.0f : 0.0f;
    const size_t i0 = (size_t)k * 64 + 2 * jp;
    *(float2*)(out + (size_t)b * N_INPUTS + i0) = r;
}

extern "C" void kernel_launch(void* const* d_in, const int* in_sizes, int n_in,
                              void* d_out, int out_size, void* d_ws, size_t ws_size,
                              hipStream_t stream) {
    const float* x   = (const float*)d_in[0];              // [B, N_INPUTS] f32
    const int*   det = (const int*)d_in[1];                // [N_DET, K] i32
    unsigned* wp   = (unsigned*)d_ws;                                  // 8 MB win partials
    unsigned* degp = (unsigned*)d_ws + (size_t)SLICES * PAIRS * WC_WORDS; // +8 MB, 1 MB deg partials

    degree_count<<<DEG_BLOCKS, 1024, 0, stream>>>(det, degp);
    dim3 grid(SLICES, PAIRS);
    inhibit<<<grid, THREADS, 0, stream>>>(x, det, wp);
    finalize<<<N_INPUTS / 64, 1024, 0, stream>>>(wp, degp, (float*)d_out);
}

// Round 2
// 94.132 us; speedup vs baseline: 1.0496x; 1.0496x over previous
//
#include <hip/hip_runtime.h>

#define N_INPUTS 16384
#define N_DET    65536
#define KD       32
#define BATCH    32
#define SLICES   16                        // det slices; slice -> fixed XCD
#define PAIRS    (BATCH / 2)               // 16 batch pairs
#define DPB      (N_DET / SLICES)          // 4096 detectors per block
#define THREADS  1024                      // 16 waves, 1 block/CU (160 KB LDS)

#define DEG_BLOCKS     64
#define DET_PER_DEGBLK (N_DET / DEG_BLOCKS)   // 1024
#define DEG_WORDS      (N_INPUTS / 4)         // 4096 u32, byte-packed u8 counts
#define WC_WORDS       (N_INPUTS / 2)         // 8192 u32: 2 inputs x 2 batches (u8)

__device__ __forceinline__ float max3f(float a, float b, float c) {
    return fmaxf(fmaxf(a, b), c);          // fuses to v_max3_f32
}

// ---------------------------------------------------------------------------
// Win-count formulation: input i spikes for batch b iff
//     win_count[b][i] == degree[i]   (degree = membership multiplicity,
// batch-independent, counted once per launch). Duplicate ids inside one
// detector are handled exactly: the winner gets 1 win but degree counts the
// duplicate slot, so win != degree -> inhibited, matching the reference.
// ---------------------------------------------------------------------------

// degree partials: block counts multiplicity of 1024 detectors into byte-
// packed LDS (per-block byte <= ~15, total degree <= ~180 < 255: carry-safe).
__global__ __launch_bounds__(1024) void degree_count(const int* __restrict__ det,
                                                     unsigned* __restrict__ degp) {
    __shared__ unsigned dl[DEG_WORDS];      // 16 KB, input i -> byte i&3 of word i>>2
    const int tid = threadIdx.x;
#pragma unroll
    for (int k = 0; k < DEG_WORDS / 1024; ++k) dl[tid + k * 1024] = 0u;
    __syncthreads();

    const int d = blockIdx.x * DET_PER_DEGBLK + tid;   // one detector per thread
    const int4* drow = (const int4*)det + (size_t)d * (KD / 4);
#pragma unroll
    for (int q = 0; q < KD / 4; ++q) {
        int4 r = drow[q];
        atomicAdd(&dl[r.x >> 2], 1u << (8 * (r.x & 3)));
        atomicAdd(&dl[r.y >> 2], 1u << (8 * (r.y & 3)));
        atomicAdd(&dl[r.z >> 2], 1u << (8 * (r.z & 3)));
        atomicAdd(&dl[r.w >> 2], 1u << (8 * (r.w & 3)));
    }
    __syncthreads();

    unsigned* out = degp + (size_t)blockIdx.x * DEG_WORDS;
#pragma unroll
    for (int k = 0; k < DEG_WORDS / 1024; ++k)
        out[tid + k * 1024] = dl[tid + k * 1024];
}

// collapse the 64 partials once (byte-lane sums <= ~180: no carry across
// lanes). 4096 threads, coalesced strided reads, ~1-2 us.
__global__ __launch_bounds__(256) void degree_reduce(const unsigned* __restrict__ degp,
                                                     unsigned* __restrict__ degf) {
    const int w = blockIdx.x * 256 + threadIdx.x;      // 0 .. DEG_WORDS-1
    unsigned s = 0;
#pragma unroll
    for (int p = 0; p < DEG_BLOCKS; ++p) s += degp[(size_t)p * DEG_WORDS + w];
    degf[w] = s;
}

// ---------------------------------------------------------------------------
// One block = (2 batch rows interleaved in LDS as float2) x (one detector
// slice). Per detector: 32-deep ds_read_b64 gather burst serves both batches;
// max via v_max3 tree; winner ID via backward cndmask chain over ids[s]
// (compile-time indices only -> no scratch; exact first-max tie-break). Then
// just TWO fire-and-forget LDS atomicAdds per detector (one winner per batch)
// into byte-packed win counters. [BYTE-IDENTICAL to round-1 inhibit.]
// ---------------------------------------------------------------------------
__global__ __launch_bounds__(THREADS) void inhibit(const float* __restrict__ x,
                                                   const int* __restrict__ det,
                                                   unsigned* __restrict__ wp) {
    __shared__ float2   xs[N_INPUTS];       // 128 KB: [id] -> (x_b0, x_b1)
    __shared__ unsigned wc[WC_WORDS];       // 32 KB: input i, batch q -> byte (i&1)*2+q

    const int slice = blockIdx.x;
    const int pair  = blockIdx.y;
    const int tid   = threadIdx.x;

#pragma unroll
    for (int k = 0; k < WC_WORDS / THREADS; ++k) wc[tid + k * THREADS] = 0u;

    // stage both rows interleaved: xs[i] = (x[b0][i], x[b1][i])
    const float4* x0 = (const float4*)(x + (size_t)(2 * pair) * N_INPUTS);
    const float4* x1 = (const float4*)(x + (size_t)(2 * pair + 1) * N_INPUTS);
    float4* xs4 = (float4*)xs;
#pragma unroll
    for (int k = 0; k < N_INPUTS / 4 / THREADS; ++k) {
        int t = tid + k * THREADS;
        float4 a = x0[t], b = x1[t];
        xs4[2 * t + 0] = make_float4(a.x, b.x, a.y, b.y);
        xs4[2 * t + 1] = make_float4(a.z, b.z, a.w, b.w);
    }
    __syncthreads();

    const int4* det4 = (const int4*)det;
#pragma unroll 1
    for (int j = 0; j < DPB / THREADS; ++j) {      // 4 detectors per thread
        const int   d    = slice * DPB + j * THREADS + tid;
        const int4* drow = det4 + (size_t)d * 8;
        int ids[KD];
#pragma unroll
        for (int q = 0; q < 8; ++q) {
            int4 r = drow[q];
            ids[q * 4 + 0] = r.x; ids[q * 4 + 1] = r.y;
            ids[q * 4 + 2] = r.z; ids[q * 4 + 3] = r.w;
        }

        float2 v[KD];                              // 32-deep ds_read_b64 burst
#pragma unroll
        for (int s = 0; s < KD; ++s) v[s] = xs[ids[s]];

        // max3 tree per batch (exact: fmax/max3 return an input bit-for-bit)
        float t0[11], t1[11];
#pragma unroll
        for (int i = 0; i < 10; ++i) {
            t0[i] = max3f(v[3 * i].x, v[3 * i + 1].x, v[3 * i + 2].x);
            t1[i] = max3f(v[3 * i].y, v[3 * i + 1].y, v[3 * i + 2].y);
        }
        t0[10] = fmaxf(v[30].x, v[31].x);
        t1[10] = fmaxf(v[30].y, v[31].y);
        float m0 = fmaxf(max3f(max3f(t0[0], t0[1], t0[2]),
                               max3f(t0[3], t0[4], t0[5]),
                               max3f(t0[6], t0[7], t0[8])),
                         fmaxf(t0[9], t0[10]));
        float m1 = fmaxf(max3f(max3f(t1[0], t1[1], t1[2]),
                               max3f(t1[3], t1[4], t1[5]),
                               max3f(t1[6], t1[7], t1[8])),
                         fmaxf(t1[9], t1[10]));

        // first-max winner ID per batch: backward overwrite chain (2 ops/slot)
        int i0 = ids[0], i1 = ids[0];
#pragma unroll
        for (int s = KD - 1; s >= 0; --s) {
            i0 = (v[s].x == m0) ? ids[s] : i0;
            i1 = (v[s].y == m1) ? ids[s] : i1;
        }

        // one win per detector per batch (byte-packed; per-slice wins <= ~25)
        atomicAdd(&wc[i0 >> 1], 1u << (8 * ((i0 & 1) * 2 + 0)));
        atomicAdd(&wc[i1 >> 1], 1u << (8 * ((i1 & 1) * 2 + 1)));
    }
    __syncthreads();

    unsigned* out = wp + (size_t)(slice * PAIRS + pair) * WC_WORDS;
#pragma unroll
    for (int k = 0; k < WC_WORDS / THREADS; ++k)
        out[tid + k * THREADS] = wc[tid + k * THREADS];
}

// ---------------------------------------------------------------------------
// finalize (round-0 shape): one thread = one (b, i). 16 coalesced u32 reads
// (sum slice win-partials; byte lanes carry-safe), 1 degree byte, compare.
// ---------------------------------------------------------------------------
__global__ __launch_bounds__(256) void finalize(const unsigned* __restrict__ wp,
                                                const unsigned* __restrict__ degf,
                                                float* __restrict__ out) {
    const int gid = blockIdx.x * 256 + threadIdx.x;   // 0 .. B*N_INPUTS-1
    const int b   = gid >> 14;
    const int i   = gid & (N_INPUTS - 1);
    const int p   = b >> 1, q = b & 1;

    unsigned wsum = 0;
#pragma unroll
    for (int s = 0; s < SLICES; ++s)
        wsum += wp[(size_t)(s * PAIRS + p) * WC_WORDS + (i >> 1)];

    const unsigned win = (wsum >> (8 * ((i & 1) * 2 + q))) & 255u;
    const unsigned deg = (degf[i >> 2] >> (8 * (i & 3))) & 255u;
    out[gid] = (win == deg) ? 1.0f : 0.0f;
}

extern "C" void kernel_launch(void* const* d_in, const int* in_sizes, int n_in,
                              void* d_out, int out_size, void* d_ws, size_t ws_size,
                              hipStream_t stream) {
    const float* x   = (const float*)d_in[0];              // [B, N_INPUTS] f32
    const int*   det = (const int*)d_in[1];                // [N_DET, K] i32
    unsigned* wp   = (unsigned*)d_ws;                                    // 8 MB win partials
    unsigned* degp = wp + (size_t)SLICES * PAIRS * WC_WORDS;             // 1 MB deg partials
    unsigned* degf = degp + (size_t)DEG_BLOCKS * DEG_WORDS;              // 16 KB final degree

    degree_count<<<DEG_BLOCKS, 1024, 0, stream>>>(det, degp);
    degree_reduce<<<DEG_WORDS / 256, 256, 0, stream>>>(degp, degf);
    dim3 grid(SLICES, PAIRS);
    inhibit<<<grid, THREADS, 0, stream>>>(x, det, wp);
    finalize<<<BATCH * N_INPUTS / 256, 256, 0, stream>>>(wp, degf, (float*)d_out);
}

// Round 3
// 92.633 us; speedup vs baseline: 1.0666x; 1.0162x over previous
//
#include <hip/hip_runtime.h>

#define N_INPUTS 16384
#define N_DET    65536
#define KD       32
#define BATCH    32
#define SLICES   16                        // det slices; slice -> fixed XCD
#define DPB      (N_DET / SLICES)          // 4096 detectors per block
#define THREADS  1024                      // 16 waves, 1 block/CU (132 KB LDS)

__device__ __forceinline__ float max3f(float a, float b, float c) {
    return fmaxf(fmaxf(a, b), c);          // fuses to v_max3_f32
}

// keep even bits of a 32-bit word -> 16-bit compaction
__device__ __forceinline__ unsigned compact_even(unsigned v) {
    v &= 0x55555555u;
    v = (v | (v >> 1)) & 0x33333333u;
    v = (v | (v >> 2)) & 0x0F0F0F0Fu;
    v = (v | (v >> 4)) & 0x00FF00FFu;
    v = (v | (v >> 8)) & 0x0000FFFFu;
    return v;
}

// ---------------------------------------------------------------------------
// prep: transpose det [N_DET][8 x int4] -> detT [8][N_DET] int4 so that
// inhibit's per-detector slot-quad loads are lane-coalesced (lane-stride 16 B
// instead of 128 B -> 8 cache lines per instruction instead of 64).
// detT[q][d] = det row d, slots 4q..4q+3 (ids order preserved exactly).
// Reads coalesced; writes land as 8 x 128B segments per wave (8 lines/op).
// ---------------------------------------------------------------------------
__global__ __launch_bounds__(1024) void prep(const int4* __restrict__ det4,
                                             int4* __restrict__ detT) {
    const int t = blockIdx.x * 1024 + threadIdx.x;
#pragma unroll
    for (int k = 0; k < 8; ++k) {
        const int g = t + k * 65536;          // 0 .. N_DET*8-1, coalesced read
        int4 r = det4[g];
        detT[(size_t)(g & 7) * N_DET + (g >> 3)] = r;
    }
}

// ---------------------------------------------------------------------------
// One block = (2 batch rows interleaved in LDS as float2) x (one detector
// slice). Per detector: one 32-deep ds_read_b64 burst serves both batches
// (max outstanding LDS loads -> latency amortized). Max via v_max3 tree;
// winner slot via backward cndmask chain (exact first-max tie-break, which
// also handles duplicate ids / exact float ties). Loser flags live as 2 bits
// per input in a 4 KB LDS word array, set by UNPREDICATED fire-and-forget
// atomicOr (ds_or_b32, no return): winner slots contribute 0 bits, so there
// is no exec-mask dance, no divergent epilogue, no store races. Pack phase
// compacts even/odd bits and writes u16 partial-mask words.
// [Identical to the 85.4us round-0 kernel except det loads go through detT.]
// ---------------------------------------------------------------------------
__global__ __launch_bounds__(THREADS) void inhibit(const float* __restrict__ x,
                                                   const int4* __restrict__ detT,
                                                   unsigned long long* __restrict__ pm) {
    __shared__ float2   xs[N_INPUTS];        // 128 KB: [id] -> (x_b0, x_b1)
    __shared__ unsigned fl[N_INPUTS / 16];   // 4 KB: bit 2p = b0-loser, 2p+1 = b1

    const int slice = blockIdx.x;
    const int pair  = blockIdx.y;
    const int tid   = threadIdx.x;

    fl[tid] = 0u;                            // 1024 words / 1024 threads

    // stage both rows interleaved: xs[i] = (x[b0][i], x[b1][i])
    const float4* x0 = (const float4*)(x + (size_t)(2 * pair) * N_INPUTS);
    const float4* x1 = (const float4*)(x + (size_t)(2 * pair + 1) * N_INPUTS);
    float4* xs4 = (float4*)xs;
#pragma unroll
    for (int k = 0; k < N_INPUTS / 4 / THREADS; ++k) {
        int t = tid + k * THREADS;
        float4 a = x0[t], b = x1[t];
        xs4[2 * t + 0] = make_float4(a.x, b.x, a.y, b.y);
        xs4[2 * t + 1] = make_float4(a.z, b.z, a.w, b.w);
    }
    __syncthreads();

#pragma unroll 1
    for (int j = 0; j < DPB / THREADS; ++j) {      // 4 detectors per thread
        const int d = slice * DPB + j * THREADS + tid;
        int ids[KD];
#pragma unroll
        for (int q = 0; q < 8; ++q) {              // lane-coalesced: stride 16B
            int4 r = detT[(size_t)q * N_DET + d];
            ids[q * 4 + 0] = r.x; ids[q * 4 + 1] = r.y;
            ids[q * 4 + 2] = r.z; ids[q * 4 + 3] = r.w;
        }

        float2 v[KD];                              // 32-deep ds_read_b64 burst
#pragma unroll
        for (int s = 0; s < KD; ++s) v[s] = xs[ids[s]];

        // max3 tree per batch (exact: fmax/max3 return an input bit-for-bit)
        float t0[11], t1[11];
#pragma unroll
        for (int i = 0; i < 10; ++i) {
            t0[i] = max3f(v[3 * i].x, v[3 * i + 1].x, v[3 * i + 2].x);
            t1[i] = max3f(v[3 * i].y, v[3 * i + 1].y, v[3 * i + 2].y);
        }
        t0[10] = fmaxf(v[30].x, v[31].x);
        t1[10] = fmaxf(v[30].y, v[31].y);
        float m0 = fmaxf(max3f(max3f(t0[0], t0[1], t0[2]),
                               max3f(t0[3], t0[4], t0[5]),
                               max3f(t0[6], t0[7], t0[8])),
                         fmaxf(t0[9], t0[10]));
        float m1 = fmaxf(max3f(max3f(t1[0], t1[1], t1[2]),
                               max3f(t1[3], t1[4], t1[5]),
                               max3f(t1[6], t1[7], t1[8])),
                         fmaxf(t1[9], t1[10]));

        // first-max slot per batch: backward overwrite chain (2 ops/slot)
        int s0 = 0, s1 = 0;
#pragma unroll
        for (int s = KD - 1; s >= 0; --s) {
            s0 = (v[s].x == m0) ? s : s0;
            s1 = (v[s].y == m1) ? s : s1;
        }

        const unsigned wm0 = 1u << s0, wm1 = 1u << s1;
#pragma unroll
        for (int s = 0; s < KD; ++s) {
            int id = ids[s];
            // lose bits: 3 minus winner bits; winner-only slot contributes 0
            unsigned lose = 3u ^ (((wm0 >> s) & 1u) | (((wm1 >> s) & 1u) << 1));
            atomicOr(&fl[id >> 4], lose << ((id & 15) * 2));  // ds_or, no rtn
        }
    }
    __syncthreads();

    // pack: word tid covers inputs [16*tid, 16*tid+15]; compact even/odd bits
    unsigned f  = fl[tid];
    unsigned b0 = compact_even(f);
    unsigned b1 = compact_even(f >> 1);
    unsigned short* pm0 =
        (unsigned short*)(pm + ((size_t)(2 * pair) * SLICES + slice) * (N_INPUTS / 64));
    unsigned short* pm1 =
        (unsigned short*)(pm + ((size_t)(2 * pair + 1) * SLICES + slice) * (N_INPUTS / 64));
    pm0[tid] = (unsigned short)b0;
    pm1[tid] = (unsigned short)b1;
}

// ---------------------------------------------------------------------------
// out[b][i] = 1.0 iff bit i clear in OR of the batch's 16 slice masks.
// ---------------------------------------------------------------------------
__global__ __launch_bounds__(256) void finalize(const unsigned* __restrict__ pm,
                                                float* __restrict__ out) {
    const int gid = blockIdx.x * 256 + threadIdx.x;   // 0 .. B*N_INPUTS-1
    const int b   = gid >> 14;
    const int i   = gid & (N_INPUTS - 1);
    unsigned acc = 0;
#pragma unroll
    for (int s = 0; s < SLICES; ++s)
        acc |= pm[((b * SLICES + s) << 9) + (i >> 5)]; // 512 u32 per partial
    out[gid] = ((acc >> (i & 31)) & 1u) ? 0.0f : 1.0f;
}

extern "C" void kernel_launch(void* const* d_in, const int* in_sizes, int n_in,
                              void* d_out, int out_size, void* d_ws, size_t ws_size,
                              hipStream_t stream) {
    const float* x   = (const float*)d_in[0];              // [B, N_INPUTS] f32
    const int*   det = (const int*)d_in[1];                // [N_DET, K] i32
    int4* detT = (int4*)d_ws;                              // 8 MB transposed det
    unsigned long long* pm =
        (unsigned long long*)((char*)d_ws + (size_t)8 * N_DET * 16); // 1 MB masks

    prep<<<N_DET / 1024, 1024, 0, stream>>>((const int4*)det, detT);
    dim3 grid(SLICES, BATCH / 2);
    inhibit<<<grid, THREADS, 0, stream>>>(x, detT, pm);
    finalize<<<BATCH * N_INPUTS / 256, 256, 0, stream>>>((const unsigned*)pm,
                                                         (float*)d_out);
}